// Round 5
// baseline (1271.816 us; speedup 1.0000x reference)
//
#include <hip/hip_runtime.h>
#include <stdint.h>

#define SEQ 128
#define BATCH 256
#define INPUT_BITS 256
#define STATE_BITS 256
#define N_IN 1024
#define N_ST 256
#define NB 16
#define RAM_WORDS 2048   // 2^16 bits / 32 bits per word

typedef unsigned long long u64;
typedef uint32_t u32x4 __attribute__((ext_vector_type(4)));

// Pack "bool as 32-bit word" -> bitmask. Each thread builds ONE output word
// from 32 consecutive source words.
__global__ __launch_bounds__(256)
void pack_bits_kernel(const u32x4* __restrict__ src, uint32_t* __restrict__ dst) {
    int i = blockIdx.x * blockDim.x + threadIdx.x;   // output word index
    const u32x4* p = src + (size_t)i * 8;
    uint32_t w = 0;
#pragma unroll
    for (int j = 0; j < 8; j++) {
        u32x4 v = __builtin_nontemporal_load(p + j);
        w |= (v.x != 0u ? 1u : 0u) << (4 * j + 0);
        w |= (v.y != 0u ? 1u : 0u) << (4 * j + 1);
        w |= (v.z != 0u ? 1u : 0u) << (4 * j + 2);
        w |= (v.w != 0u ? 1u : 0u) << (4 * j + 3);
    }
    dst[i] = w;
}

// Neuron-sliced automaton. Wave = one batch element; block = 8 waves sharing
// one neuron slice; slice = blockIdx & 7 (XCD round-robin heuristic) so each
// XCD's L2 caches only its 1MB input-table slice + 2MB state tables.
// Cross-slice io exchange: tagged agent-scope relaxed atomics, double-buffered
// by step parity (deadlock-free: phase1@t+2 is ordered after phase2@t+1 which
// waited on all peers' phase1@t+1, each ordered after that peer's phase2@t —
// i.e. all consumers of parity-p step-t words are done before overwrite).
__global__ __launch_bounds__(512)
void ram_sliced_kernel(
    const uint32_t* __restrict__ pseq,   // packed [SEQ][BATCH][8]
    const uint32_t* __restrict__ pinit,  // packed [BATCH][8]
    const int*      __restrict__ input_conn, // [N_IN][16]
    const int*      __restrict__ state_conn, // [N_ST][16]
    const uint32_t* __restrict__ pim,    // packed input tables [N_IN][2048]
    const uint32_t* __restrict__ psm,    // packed state tables [N_ST][2048]
    u64*            __restrict__ ex,     // exchange [2][BATCH][32] u64
    int*            __restrict__ outs,   // [SEQ][BATCH][N_IN]
    int*            __restrict__ final_state) // [BATCH][N_ST]
{
    // per-wave context rows: [seq 8 | state 8 | io 32] words
    __shared__ uint32_t ctx[8 * 48];

    const int tid  = threadIdx.x;
    const int lane = tid & 63;
    const int w    = tid >> 6;          // wave id = batch lane (0..7)
    const int s    = blockIdx.x & 7;    // neuron slice / XCD
    const int j    = blockIdx.x >> 3;   // batch group (0..31)
    const int gb   = j * 8 + w;         // global batch element
    const int base = w * 48;

    // Connection registers, packed as (ctx word index << 8) | bitpos.
    uint32_t icr[2][16];
#pragma unroll
    for (int m = 0; m < 2; m++) {
        int n = s * 128 + lane + 64 * m;
#pragma unroll
        for (int k = 0; k < 16; k++) {
            int c = input_conn[n * 16 + k];
            int sel = (c < 256) ? (c >> 5) : (8 + ((c - 256) >> 5));
            icr[m][k] = ((uint32_t)(base + sel) << 8) | (uint32_t)(c & 31);
        }
    }
    uint32_t scr[4][16];
#pragma unroll
    for (int m = 0; m < 4; m++) {
        int n = lane + 64 * m;
#pragma unroll
        for (int k = 0; k < 16; k++) {
            int c = state_conn[n * 16 + k];
            int sel = (c < 1024) ? (16 + (c >> 5)) : (8 + ((c - 1024) >> 5));
            scr[m][k] = ((uint32_t)(base + sel) << 8) | (uint32_t)(c & 31);
        }
    }

    // Initial state words + first seq-word prefetch (wave-internal LDS only).
    if (lane < 8) ctx[base + 8 + lane] = pinit[gb * 8 + lane];
    uint32_t sreg = 0;
    if (lane < 8) sreg = pseq[(size_t)gb * 8 + lane];  // t = 0

    uint32_t sb0 = 0, sb1 = 0, sb2 = 0, sb3 = 0;

    for (int t = 0; t < SEQ; t++) {
        const u64 tag = (u64)(t + 1);

        if (lane < 8) ctx[base + lane] = sreg;                 // seq words for t
        if (t + 1 < SEQ && lane < 8)
            sreg = pseq[((size_t)(t + 1) * BATCH + gb) * 8 + lane];

        // ---- Phase 1: this slice's 128 input neurons for batch gb ----
        uint32_t bit0, bit1;
        {
            uint32_t a0 = 0, a1 = 0;
#pragma unroll
            for (int k = 0; k < 16; k++) {
                uint32_t r0 = icr[0][k], r1 = icr[1][k];
                a0 |= ((ctx[r0 >> 8] >> (r0 & 31)) & 1u) << k;
                a1 |= ((ctx[r1 >> 8] >> (r1 & 31)) & 1u) << k;
            }
            int n0 = s * 128 + lane, n1 = n0 + 64;
            uint32_t t0 = pim[((size_t)n0 << 11) + (a0 >> 5)];
            uint32_t t1 = pim[((size_t)n1 << 11) + (a1 >> 5)];
            bit0 = (t0 >> (a0 & 31)) & 1u;
            bit1 = (t1 >> (a1 & 31)) & 1u;
            int* op = outs + ((size_t)t * BATCH + gb) * N_IN + n0;
            __builtin_nontemporal_store((int)bit0, op);
            __builtin_nontemporal_store((int)bit1, op + 64);
        }
        u64 m0 = __ballot(bit0 != 0u);
        u64 m1 = __ballot(bit1 != 0u);

        // Publish 128 io bits as 4 tagged u64 (agent-scope relaxed atomics).
        if (lane < 4) {
            uint32_t half = (lane < 2) ? (uint32_t)(m0 >> (lane * 32))
                                       : (uint32_t)(m1 >> ((lane - 2) * 32));
            u64 v = ((tag << 16) | (half & 0xFFFFu))
                  | ((((tag << 16) | (half >> 16))) << 32);
            __hip_atomic_store(&ex[(((size_t)(t & 1) * BATCH) + gb) * 32 + s * 4 + lane],
                               v, __ATOMIC_RELAXED, __HIP_MEMORY_SCOPE_AGENT);
        }

        // ---- Gather all 1024 io bits for batch gb (spin on tags) ----
        if (lane < 32) {
            const u64* p = &ex[(((size_t)(t & 1) * BATCH) + gb) * 32 + lane];
            u64 v; int guard = 0;
            for (;;) {
                v = __hip_atomic_load(p, __ATOMIC_RELAXED, __HIP_MEMORY_SCOPE_AGENT);
                if ((((v >> 16) & 0xFFFFull) == tag) && ((v >> 48) == tag)) break;
                if (++guard > (1 << 22)) break;   // safety bailout (visible failure, no hang)
                __builtin_amdgcn_s_sleep(1);
            }
            ctx[base + 16 + lane] =
                (uint32_t)(v & 0xFFFFu) | (((uint32_t)(v >> 32) & 0xFFFFu) << 16);
        }

        // ---- Phase 2: all 256 state neurons (replicated per slice) ----
        {
            uint32_t a0 = 0, a1 = 0, a2 = 0, a3 = 0;
#pragma unroll
            for (int k = 0; k < 16; k++) {
                uint32_t r0 = scr[0][k], r1 = scr[1][k], r2 = scr[2][k], r3 = scr[3][k];
                a0 |= ((ctx[r0 >> 8] >> (r0 & 31)) & 1u) << k;
                a1 |= ((ctx[r1 >> 8] >> (r1 & 31)) & 1u) << k;
                a2 |= ((ctx[r2 >> 8] >> (r2 & 31)) & 1u) << k;
                a3 |= ((ctx[r3 >> 8] >> (r3 & 31)) & 1u) << k;
            }
            uint32_t t0 = psm[((size_t)(lane      ) << 11) + (a0 >> 5)];
            uint32_t t1 = psm[((size_t)(lane +  64) << 11) + (a1 >> 5)];
            uint32_t t2 = psm[((size_t)(lane + 128) << 11) + (a2 >> 5)];
            uint32_t t3 = psm[((size_t)(lane + 192) << 11) + (a3 >> 5)];
            sb0 = (t0 >> (a0 & 31)) & 1u;
            sb1 = (t1 >> (a1 & 31)) & 1u;
            sb2 = (t2 >> (a2 & 31)) & 1u;
            sb3 = (t3 >> (a3 & 31)) & 1u;
        }
        u64 q0 = __ballot(sb0 != 0u);
        u64 q1 = __ballot(sb1 != 0u);
        u64 q2 = __ballot(sb2 != 0u);
        u64 q3 = __ballot(sb3 != 0u);
        if (lane < 8) {
            int mi = lane >> 1;
            u64 qq = (mi == 0) ? q0 : (mi == 1) ? q1 : (mi == 2) ? q2 : q3;
            ctx[base + 8 + lane] = (uint32_t)(qq >> ((lane & 1) * 32));
        }
    }

    if (s == 0) {
        final_state[(size_t)gb * N_ST + lane +   0] = (int)sb0;
        final_state[(size_t)gb * N_ST + lane +  64] = (int)sb1;
        final_state[(size_t)gb * N_ST + lane + 128] = (int)sb2;
        final_state[(size_t)gb * N_ST + lane + 192] = (int)sb3;
    }
}

// ---------------- Fallback (ws too small): round-4 kernel, raw tables -------
__global__ __launch_bounds__(1024)
void ram_automaton_fallback(
    const uint32_t* __restrict__ seq_bits, const uint32_t* __restrict__ init_state,
    const int* __restrict__ input_conn, const int* __restrict__ state_conn,
    const uint32_t* __restrict__ im_raw, const uint32_t* __restrict__ sm_raw,
    int* __restrict__ outs, int* __restrict__ final_state)
{
    __shared__ uint32_t c0[16];
    __shared__ uint32_t c1[40];
    const int b = blockIdx.x, tid = threadIdx.x, lane = tid & 63;
    int ic[NB];
#pragma unroll
    for (int k = 0; k < NB; k++) ic[k] = input_conn[tid * NB + k];
    int sc[NB];
    if (tid < N_ST) {
#pragma unroll
        for (int k = 0; k < NB; k++) sc[k] = state_conn[tid * NB + k];
    }
    uint32_t nsbit = 0;
    if (tid < N_ST) nsbit = (init_state[(size_t)b * STATE_BITS + tid] != 0u) ? 1u : 0u;
    uint32_t inbit = 0;
    if (tid < INPUT_BITS) inbit = seq_bits[(size_t)b * INPUT_BITS + tid];
    for (int t = 0; t < SEQ; t++) {
        if (tid < INPUT_BITS) {
            u64 mi = __ballot(inbit != 0u);
            u64 ms = __ballot(nsbit != 0u);
            if ((lane & 31) == 0) {
                c0[tid >> 5] = (uint32_t)(mi >> (lane & 32));
                uint32_t wsd = (uint32_t)(ms >> (lane & 32));
                c0[8 + (tid >> 5)] = wsd; c1[32 + (tid >> 5)] = wsd;
            }
        }
        __syncthreads();
        if (t + 1 < SEQ && tid < INPUT_BITS)
            inbit = seq_bits[((size_t)(t + 1) * BATCH + b) * INPUT_BITS + tid];
        {
            int addr = 0;
#pragma unroll
            for (int k = 0; k < NB; k++) {
                int c = ic[k];
                addr |= (int)((c0[c >> 5] >> (c & 31)) & 1u) << k;
            }
            uint32_t bit = (im_raw[((size_t)tid << 16) + (size_t)addr] != 0u) ? 1u : 0u;
            __builtin_nontemporal_store((int)bit, outs + ((size_t)t * BATCH + b) * N_IN + tid);
            u64 m = __ballot(bit != 0u);
            if (lane == 0) { c1[tid >> 5] = (uint32_t)m; c1[(tid >> 5) + 1] = (uint32_t)(m >> 32); }
        }
        __syncthreads();
        if (tid < N_ST) {
            int addr = 0;
#pragma unroll
            for (int k = 0; k < NB; k++) {
                int c = sc[k];
                addr |= (int)((c1[c >> 5] >> (c & 31)) & 1u) << k;
            }
            nsbit = (sm_raw[((size_t)tid << 16) + (size_t)addr] != 0u) ? 1u : 0u;
        }
        __syncthreads();
    }
    if (tid < N_ST) final_state[(size_t)b * N_ST + tid] = (int)nsbit;
}

extern "C" void kernel_launch(void* const* d_in, const int* in_sizes, int n_in,
                              void* d_out, int out_size, void* d_ws, size_t ws_size,
                              hipStream_t stream) {
    const uint32_t* seq        = (const uint32_t*)d_in[0];
    const uint32_t* init_state = (const uint32_t*)d_in[1];
    const int*      input_conn = (const int*)d_in[2];
    const uint32_t* input_mem  = (const uint32_t*)d_in[3];
    const int*      state_conn = (const int*)d_in[4];
    const uint32_t* state_mem  = (const uint32_t*)d_in[5];

    int* outs = (int*)d_out;                       // [SEQ][BATCH][N_IN]
    int* fin  = outs + (size_t)SEQ * BATCH * N_IN; // [BATCH][N_ST]

    const size_t ex_u64    = (size_t)2 * BATCH * 32;        // 16384 u64 = 128 KB
    const size_t pim_words = (size_t)N_IN * RAM_WORDS;      // 2,097,152
    const size_t psm_words = (size_t)N_ST * RAM_WORDS;      //   524,288
    const size_t pseq_words = (size_t)SEQ * BATCH * 8;      //   262,144
    const size_t pinit_words = (size_t)BATCH * 8;           //     2,048
    const size_t need = ex_u64 * 8 +
        (pim_words + psm_words + pseq_words + pinit_words) * 4;

    if (ws_size >= need) {
        u64*      ex    = (u64*)d_ws;
        uint32_t* pim   = (uint32_t*)(ex + ex_u64);
        uint32_t* psm   = pim + pim_words;
        uint32_t* pseq  = psm + psm_words;
        uint32_t* pinit = pseq + pseq_words;

        hipLaunchKernelGGL(pack_bits_kernel, dim3((unsigned)(pim_words / 256)),
                           dim3(256), 0, stream, (const u32x4*)input_mem, pim);
        hipLaunchKernelGGL(pack_bits_kernel, dim3((unsigned)(psm_words / 256)),
                           dim3(256), 0, stream, (const u32x4*)state_mem, psm);
        hipLaunchKernelGGL(pack_bits_kernel, dim3((unsigned)(pseq_words / 256)),
                           dim3(256), 0, stream, (const u32x4*)seq, pseq);
        hipLaunchKernelGGL(pack_bits_kernel, dim3((unsigned)(pinit_words / 256)),
                           dim3(256), 0, stream, (const u32x4*)init_state, pinit);

        hipLaunchKernelGGL(ram_sliced_kernel, dim3(BATCH), dim3(512), 0, stream,
                           pseq, pinit, input_conn, state_conn, pim, psm,
                           ex, outs, fin);
    } else {
        hipLaunchKernelGGL(ram_automaton_fallback, dim3(BATCH), dim3(1024), 0, stream,
                           seq, init_state, input_conn, state_conn,
                           input_mem, state_mem, outs, fin);
    }
}

// Round 6
// 1156.096 us; speedup vs baseline: 1.1001x; 1.1001x over previous
//
#include <hip/hip_runtime.h>
#include <stdint.h>

#define SEQ 128
#define BATCH 256
#define INPUT_BITS 256
#define STATE_BITS 256
#define N_IN 1024
#define N_ST 256
#define NB 16
#define RAM_WORDS 2048   // 2^16 bits / 32 bits per word

typedef unsigned long long u64;
typedef uint32_t u32x4 __attribute__((ext_vector_type(4)));

// Pack "bool as 32-bit word" -> bitmask. Each thread builds ONE output word
// from 32 consecutive source words.
__global__ __launch_bounds__(256)
void pack_bits_kernel(const u32x4* __restrict__ src, uint32_t* __restrict__ dst) {
    int i = blockIdx.x * blockDim.x + threadIdx.x;   // output word index
    const u32x4* p = src + (size_t)i * 8;
    uint32_t w = 0;
#pragma unroll
    for (int j = 0; j < 8; j++) {
        u32x4 v = __builtin_nontemporal_load(p + j);
        w |= (v.x != 0u ? 1u : 0u) << (4 * j + 0);
        w |= (v.y != 0u ? 1u : 0u) << (4 * j + 1);
        w |= (v.z != 0u ? 1u : 0u) << (4 * j + 2);
        w |= (v.w != 0u ? 1u : 0u) << (4 * j + 3);
    }
    dst[i] = w;
}

// Neuron-sliced automaton. Wave = one batch element; slice = blockIdx & 7
// (XCD round-robin) so each XCD's L2 caches only its 1MB input-table slice +
// 2MB state tables. Cross-slice io exchange: tagged agent-scope relaxed
// atomics, double-buffered by step parity (deadlock-free: producer's
// phase1@t+2 is ordered after its gather@t+1, which required all slices'
// publish@t+1, each ordered after that slice's gather@t — so every consumer
// of (gb,t) words is done before they're overwritten).
//
// KEY (round 6): wave w of block b carries gb = (b>>3) + 32*w — the 8 waves
// of one CU belong to 8 DIFFERENT exchange groups, so a gather stall in one
// chain overlaps with compute of the other 7 (round 5 had all 8 waves in the
// same group -> whole-CU stalls, VALUBusy 22%).
__global__ __launch_bounds__(512)
void ram_sliced_kernel(
    const uint32_t* __restrict__ pseq,   // packed [SEQ][BATCH][8]
    const uint32_t* __restrict__ pinit,  // packed [BATCH][8]
    const int*      __restrict__ input_conn, // [N_IN][16]
    const int*      __restrict__ state_conn, // [N_ST][16]
    const uint32_t* __restrict__ pim,    // packed input tables [N_IN][2048]
    const uint32_t* __restrict__ psm,    // packed state tables [N_ST][2048]
    u64*            __restrict__ ex,     // exchange [2][BATCH][32] u64
    int*            __restrict__ outs,   // [SEQ][BATCH][N_IN]
    int*            __restrict__ final_state) // [BATCH][N_ST]
{
    // per-wave context rows: [seq 8 | state 8 | io 32] words
    __shared__ uint32_t ctx[8 * 48];

    const int tid  = threadIdx.x;
    const int lane = tid & 63;
    const int w    = tid >> 6;          // wave id (0..7)
    const int s    = blockIdx.x & 7;    // neuron slice / XCD
    const int q    = blockIdx.x >> 3;   // 0..31
    const int gb   = (q + (w << 5)) & 255;  // decorrelated batch element
    const int base = w * 48;

    // Connection registers, packed as (ctx word index << 8) | bitpos.
    uint32_t icr[2][16];
#pragma unroll
    for (int m = 0; m < 2; m++) {
        int n = s * 128 + lane + 64 * m;
#pragma unroll
        for (int k = 0; k < 16; k++) {
            int c = input_conn[n * 16 + k];
            int sel = (c < 256) ? (c >> 5) : (8 + ((c - 256) >> 5));
            icr[m][k] = ((uint32_t)(base + sel) << 8) | (uint32_t)(c & 31);
        }
    }
    uint32_t scr[4][16];
#pragma unroll
    for (int m = 0; m < 4; m++) {
        int n = lane + 64 * m;
#pragma unroll
        for (int k = 0; k < 16; k++) {
            int c = state_conn[n * 16 + k];
            int sel = (c < 1024) ? (16 + (c >> 5)) : (8 + ((c - 1024) >> 5));
            scr[m][k] = ((uint32_t)(base + sel) << 8) | (uint32_t)(c & 31);
        }
    }

    // Initial state words + first seq-word prefetch (wave-internal LDS only).
    if (lane < 8) ctx[base + 8 + lane] = pinit[gb * 8 + lane];
    uint32_t sreg = 0;
    if (lane < 8) sreg = pseq[(size_t)gb * 8 + lane];  // t = 0

    uint32_t sb0 = 0, sb1 = 0, sb2 = 0, sb3 = 0;

    for (int t = 0; t < SEQ; t++) {
        const u64 tag = (u64)(t + 1);

        if (lane < 8) ctx[base + lane] = sreg;                 // seq words for t
        if (t + 1 < SEQ && lane < 8)
            sreg = pseq[((size_t)(t + 1) * BATCH + gb) * 8 + lane];

        // ---- Phase 1: this slice's 128 input neurons for batch gb ----
        uint32_t bit0, bit1;
        int n0 = s * 128 + lane;
        {
            uint32_t a0 = 0, a1 = 0;
#pragma unroll
            for (int k = 0; k < 16; k++) {
                uint32_t r0 = icr[0][k], r1 = icr[1][k];
                a0 |= ((ctx[r0 >> 8] >> (r0 & 31)) & 1u) << k;
                a1 |= ((ctx[r1 >> 8] >> (r1 & 31)) & 1u) << k;
            }
            uint32_t t0 = pim[((size_t)n0 << 11) + (a0 >> 5)];
            uint32_t t1 = pim[((size_t)(n0 + 64) << 11) + (a1 >> 5)];
            bit0 = (t0 >> (a0 & 31)) & 1u;
            bit1 = (t1 >> (a1 & 31)) & 1u;
        }
        u64 m0 = __ballot(bit0 != 0u);
        u64 m1 = __ballot(bit1 != 0u);

        // Publish FIRST (producer latency off the critical path), then store outs.
        if (lane < 4) {
            uint32_t half = (lane < 2) ? (uint32_t)(m0 >> (lane * 32))
                                       : (uint32_t)(m1 >> ((lane - 2) * 32));
            u64 v = ((tag << 16) | (half & 0xFFFFu))
                  | ((((tag << 16) | (half >> 16))) << 32);
            __hip_atomic_store(&ex[(((size_t)(t & 1) * BATCH) + gb) * 32 + s * 4 + lane],
                               v, __ATOMIC_RELAXED, __HIP_MEMORY_SCOPE_AGENT);
        }
        {
            int* op = outs + ((size_t)t * BATCH + gb) * N_IN + n0;
            __builtin_nontemporal_store((int)bit0, op);
            __builtin_nontemporal_store((int)bit1, op + 64);
        }

        // ---- Gather all 1024 io bits for batch gb (spin on tags) ----
        if (lane < 32) {
            const u64* p = &ex[(((size_t)(t & 1) * BATCH) + gb) * 32 + lane];
            u64 v; int guard = 0;
            for (;;) {
                v = __hip_atomic_load(p, __ATOMIC_RELAXED, __HIP_MEMORY_SCOPE_AGENT);
                if ((((v >> 16) & 0xFFFFull) == tag) && ((v >> 48) == tag)) break;
                if (++guard > (1 << 22)) break;   // visible failure, no hang
                __builtin_amdgcn_s_sleep(1);
            }
            ctx[base + 16 + lane] =
                (uint32_t)(v & 0xFFFFu) | (((uint32_t)(v >> 32) & 0xFFFFu) << 16);
        }

        // ---- Phase 2: all 256 state neurons (replicated per slice) ----
        {
            uint32_t a0 = 0, a1 = 0, a2 = 0, a3 = 0;
#pragma unroll
            for (int k = 0; k < 16; k++) {
                uint32_t r0 = scr[0][k], r1 = scr[1][k], r2 = scr[2][k], r3 = scr[3][k];
                a0 |= ((ctx[r0 >> 8] >> (r0 & 31)) & 1u) << k;
                a1 |= ((ctx[r1 >> 8] >> (r1 & 31)) & 1u) << k;
                a2 |= ((ctx[r2 >> 8] >> (r2 & 31)) & 1u) << k;
                a3 |= ((ctx[r3 >> 8] >> (r3 & 31)) & 1u) << k;
            }
            uint32_t t0 = psm[((size_t)(lane      ) << 11) + (a0 >> 5)];
            uint32_t t1 = psm[((size_t)(lane +  64) << 11) + (a1 >> 5)];
            uint32_t t2 = psm[((size_t)(lane + 128) << 11) + (a2 >> 5)];
            uint32_t t3 = psm[((size_t)(lane + 192) << 11) + (a3 >> 5)];
            sb0 = (t0 >> (a0 & 31)) & 1u;
            sb1 = (t1 >> (a1 & 31)) & 1u;
            sb2 = (t2 >> (a2 & 31)) & 1u;
            sb3 = (t3 >> (a3 & 31)) & 1u;
        }
        u64 q0 = __ballot(sb0 != 0u);
        u64 q1 = __ballot(sb1 != 0u);
        u64 q2 = __ballot(sb2 != 0u);
        u64 q3 = __ballot(sb3 != 0u);
        if (lane < 8) {
            int mi = lane >> 1;
            u64 qq = (mi == 0) ? q0 : (mi == 1) ? q1 : (mi == 2) ? q2 : q3;
            ctx[base + 8 + lane] = (uint32_t)(qq >> ((lane & 1) * 32));
        }
    }

    if (s == 0) {
        final_state[(size_t)gb * N_ST + lane +   0] = (int)sb0;
        final_state[(size_t)gb * N_ST + lane +  64] = (int)sb1;
        final_state[(size_t)gb * N_ST + lane + 128] = (int)sb2;
        final_state[(size_t)gb * N_ST + lane + 192] = (int)sb3;
    }
}

// ---------------- Fallback (ws too small): round-4 kernel, raw tables -------
__global__ __launch_bounds__(1024)
void ram_automaton_fallback(
    const uint32_t* __restrict__ seq_bits, const uint32_t* __restrict__ init_state,
    const int* __restrict__ input_conn, const int* __restrict__ state_conn,
    const uint32_t* __restrict__ im_raw, const uint32_t* __restrict__ sm_raw,
    int* __restrict__ outs, int* __restrict__ final_state)
{
    __shared__ uint32_t c0[16];
    __shared__ uint32_t c1[40];
    const int b = blockIdx.x, tid = threadIdx.x, lane = tid & 63;
    int ic[NB];
#pragma unroll
    for (int k = 0; k < NB; k++) ic[k] = input_conn[tid * NB + k];
    int sc[NB];
    if (tid < N_ST) {
#pragma unroll
        for (int k = 0; k < NB; k++) sc[k] = state_conn[tid * NB + k];
    }
    uint32_t nsbit = 0;
    if (tid < N_ST) nsbit = (init_state[(size_t)b * STATE_BITS + tid] != 0u) ? 1u : 0u;
    uint32_t inbit = 0;
    if (tid < INPUT_BITS) inbit = seq_bits[(size_t)b * INPUT_BITS + tid];
    for (int t = 0; t < SEQ; t++) {
        if (tid < INPUT_BITS) {
            u64 mi = __ballot(inbit != 0u);
            u64 ms = __ballot(nsbit != 0u);
            if ((lane & 31) == 0) {
                c0[tid >> 5] = (uint32_t)(mi >> (lane & 32));
                uint32_t wsd = (uint32_t)(ms >> (lane & 32));
                c0[8 + (tid >> 5)] = wsd; c1[32 + (tid >> 5)] = wsd;
            }
        }
        __syncthreads();
        if (t + 1 < SEQ && tid < INPUT_BITS)
            inbit = seq_bits[((size_t)(t + 1) * BATCH + b) * INPUT_BITS + tid];
        {
            int addr = 0;
#pragma unroll
            for (int k = 0; k < NB; k++) {
                int c = ic[k];
                addr |= (int)((c0[c >> 5] >> (c & 31)) & 1u) << k;
            }
            uint32_t bit = (im_raw[((size_t)tid << 16) + (size_t)addr] != 0u) ? 1u : 0u;
            __builtin_nontemporal_store((int)bit, outs + ((size_t)t * BATCH + b) * N_IN + tid);
            u64 m = __ballot(bit != 0u);
            if (lane == 0) { c1[tid >> 5] = (uint32_t)m; c1[(tid >> 5) + 1] = (uint32_t)(m >> 32); }
        }
        __syncthreads();
        if (tid < N_ST) {
            int addr = 0;
#pragma unroll
            for (int k = 0; k < NB; k++) {
                int c = sc[k];
                addr |= (int)((c1[c >> 5] >> (c & 31)) & 1u) << k;
            }
            nsbit = (sm_raw[((size_t)tid << 16) + (size_t)addr] != 0u) ? 1u : 0u;
        }
        __syncthreads();
    }
    if (tid < N_ST) final_state[(size_t)b * N_ST + tid] = (int)nsbit;
}

extern "C" void kernel_launch(void* const* d_in, const int* in_sizes, int n_in,
                              void* d_out, int out_size, void* d_ws, size_t ws_size,
                              hipStream_t stream) {
    const uint32_t* seq        = (const uint32_t*)d_in[0];
    const uint32_t* init_state = (const uint32_t*)d_in[1];
    const int*      input_conn = (const int*)d_in[2];
    const uint32_t* input_mem  = (const uint32_t*)d_in[3];
    const int*      state_conn = (const int*)d_in[4];
    const uint32_t* state_mem  = (const uint32_t*)d_in[5];

    int* outs = (int*)d_out;                       // [SEQ][BATCH][N_IN]
    int* fin  = outs + (size_t)SEQ * BATCH * N_IN; // [BATCH][N_ST]

    const size_t ex_u64    = (size_t)2 * BATCH * 32;        // 16384 u64 = 128 KB
    const size_t pim_words = (size_t)N_IN * RAM_WORDS;      // 2,097,152
    const size_t psm_words = (size_t)N_ST * RAM_WORDS;      //   524,288
    const size_t pseq_words = (size_t)SEQ * BATCH * 8;      //   262,144
    const size_t pinit_words = (size_t)BATCH * 8;           //     2,048
    const size_t need = ex_u64 * 8 +
        (pim_words + psm_words + pseq_words + pinit_words) * 4;

    if (ws_size >= need) {
        u64*      ex    = (u64*)d_ws;
        uint32_t* pim   = (uint32_t*)(ex + ex_u64);
        uint32_t* psm   = pim + pim_words;
        uint32_t* pseq  = psm + psm_words;
        uint32_t* pinit = pseq + pseq_words;

        hipLaunchKernelGGL(pack_bits_kernel, dim3((unsigned)(pim_words / 256)),
                           dim3(256), 0, stream, (const u32x4*)input_mem, pim);
        hipLaunchKernelGGL(pack_bits_kernel, dim3((unsigned)(psm_words / 256)),
                           dim3(256), 0, stream, (const u32x4*)state_mem, psm);
        hipLaunchKernelGGL(pack_bits_kernel, dim3((unsigned)(pseq_words / 256)),
                           dim3(256), 0, stream, (const u32x4*)seq, pseq);
        hipLaunchKernelGGL(pack_bits_kernel, dim3((unsigned)(pinit_words / 256)),
                           dim3(256), 0, stream, (const u32x4*)init_state, pinit);

        hipLaunchKernelGGL(ram_sliced_kernel, dim3(BATCH), dim3(512), 0, stream,
                           pseq, pinit, input_conn, state_conn, pim, psm,
                           ex, outs, fin);
    } else {
        hipLaunchKernelGGL(ram_automaton_fallback, dim3(BATCH), dim3(1024), 0, stream,
                           seq, init_state, input_conn, state_conn,
                           input_mem, state_mem, outs, fin);
    }
}